// Round 7
// baseline (167.480 us; speedup 1.0000x reference)
//
#include <hip/hip_runtime.h>

typedef _Float16 f16;
typedef f16 f16x8 __attribute__((ext_vector_type(8)));
typedef float f32x4 __attribute__((ext_vector_type(4)));
typedef unsigned short u16;

// ---------------------------------------------------------------------------
// Swizzled fp16 layouts (16B = 8-f16 units, BK=32 K-tiles), M-block = 48:
// A (LDS, 48x512): row m, col c -> kt=c>>5, g=(c>>3)&3, j=c&7;
//   u = m*4 + (g ^ ((m>>1)&3));  f16 off = kt*1536 + u*8 + j
// W [256,K]: n,c -> kt=c>>5, g=(c>>3)&3, j=c&7; u = n*4 + (g^((n>>1)&3));
//   off = kt*8192 + u*8 + j
// H (LDS, 48x256): m,k -> g=k>>3; u = m*32 + (g ^ ((m>>1)&7))
// ---------------------------------------------------------------------------

// ---------------------------------------------------------------------------
// Column decode table: col -> (src scalar idx, freq, kind)
// kind: 0 raw, 1 sin, 2 cos, 3 zero.  enc = src | f<<5 | kind<<9
// ---------------------------------------------------------------------------
struct FT {
  u16 v[256];
  static constexpr u16 enc(int s, int f, int k) {
    return (u16)(s | (f << 5) | (k << 9));
  }
  constexpr void p3(int base, int F, int src) {
    v[base + 0] = enc(src + 0, 0, 0);
    v[base + 1] = enc(src + 1, 0, 0);
    v[base + 2] = enc(src + 2, 0, 0);
    for (int f = 0; f < F; ++f)
      for (int r = 0; r < 6; ++r) {
        int comp = (r < 3) ? r : r - 3;
        v[base + 3 + f * 6 + r] = enc(src + comp, f, (r < 3) ? 1 : 2);
      }
  }
  constexpr void p1(int base, int F, int src) {
    v[base] = enc(src, 0, 0);
    for (int f = 0; f < F; ++f) {
      v[base + 1 + 2 * f] = enc(src, f, 1);
      v[base + 2 + 2 * f] = enc(src, f, 2);
    }
  }
  constexpr FT() : v{} {
    p3(0, 10, 0);     // hit_pos_emb   (q)          [0..62]
    p1(63, 4, 3);     // density_emb                [63..71]
    p3(72, 10, 4);    // smoothed_emb  (sp)         [72..134]
    p3(135, 10, 7);   // var_emb       (var)        [135..197]
    p3(198, 4, 10);   // hit_dir_emb   (ray dir)    [198..224]
    p3(225, 4, 13);   // dirs_emb      (dir)        [225..251]
    v[252] = enc(16, 0, 0);  // normals
    v[253] = enc(17, 0, 0);
    v[254] = enc(18, 0, 0);
    v[255] = enc(0, 0, 3);   // pad col
  }
};
__constant__ FT ftab = FT();

// ---------------------------------------------------------------------------
// Uniform grid for ball query: 10x10x10 cells, cell size 0.1 = RADIUS.
// ---------------------------------------------------------------------------
__device__ float4 g_sorted[4096];   // x,y,z, w = bitcast(original index)
__device__ int    g_cellStart[1001];

// ---------------------------------------------------------------------------
// Kernel 0 (merged setup): blocks 0..255 = weight prep fp32->fp16 swizzled;
// block 256 = grid build. Branch is block-uniform -> inner barriers safe.
// ---------------------------------------------------------------------------
__global__ __launch_bounds__(1024) void setup_kernel(
    const float* __restrict__ parts,
    const float* __restrict__ W0, const float* __restrict__ W1,
    const float* __restrict__ W2,
    f16* __restrict__ w0f, f16* __restrict__ w1f, f16* __restrict__ w2f)
{
  const int tid = threadIdx.x;
  if (blockIdx.x < 256) {
    // ---------------- weight prep ----------------
    int i = blockIdx.x * 1024 + tid;        // 0 .. 262143
    float v; f16* pf; int n, c;
    if (i < 131072) {
      n = i >> 9; c = i & 511;
      v = (c < 255) ? W0[n * 511 + c] : ((c == 255) ? 0.0f : W0[n * 511 + (c - 1)]);
      pf = w0f;
    } else if (i < 196608) {
      int j = i - 131072; n = j >> 8; c = j & 255; v = W1[j]; pf = w1f;
    } else {
      int j = i - 196608; n = j >> 8; c = j & 255; v = W2[j]; pf = w2f;
    }
    int kt = c >> 5, g = (c >> 3) & 3, jj = c & 7;
    int u = n * 4 + (g ^ ((n >> 1) & 3));
    pf[kt * 8192 + u * 8 + jj] = (f16)v;
  } else {
    // ---------------- grid build ----------------
    __shared__ int cnt[1000];
    __shared__ int pos[1000];
    __shared__ int wpre[125];
    for (int j = tid; j < 1000; j += 1024) cnt[j] = 0;
    __syncthreads();

    float px[4], py[4], pz[4];
    int cd[4];
    #pragma unroll
    for (int t = 0; t < 4; ++t) {
      int i = tid + t * 1024;
      float x = parts[3 * i], y = parts[3 * i + 1], z = parts[3 * i + 2];
      int cx = min(max((int)(x * 10.0f), 0), 9);
      int cy = min(max((int)(y * 10.0f), 0), 9);
      int cz = min(max((int)(z * 10.0f), 0), 9);
      cd[t] = (cz * 10 + cy) * 10 + cx;
      px[t] = x; py[t] = y; pz[t] = z;
      atomicAdd(&cnt[cd[t]], 1);
    }
    __syncthreads();

    if (tid < 125) {
      int s = 0;
      #pragma unroll
      for (int k = 0; k < 8; ++k) s += cnt[tid * 8 + k];
      wpre[tid] = s;
    }
    __syncthreads();
    if (tid == 0) {
      int s = 0;
      for (int c = 0; c < 125; ++c) { int t = wpre[c]; wpre[c] = s; s += t; }
    }
    __syncthreads();
    if (tid < 125) {
      int run = wpre[tid];
      #pragma unroll
      for (int k = 0; k < 8; ++k) {
        int c = tid * 8 + k;
        int n = cnt[c];
        pos[c] = run;
        g_cellStart[c] = run;
        run += n;
      }
    }
    if (tid == 0) g_cellStart[1000] = 4096;
    __syncthreads();

    #pragma unroll
    for (int t = 0; t < 4; ++t) {
      int p = atomicAdd(&pos[cd[t]], 1);
      g_sorted[p] = make_float4(px[t], py[t], pz[t], __int_as_float(tid + t * 1024));
    }
  }
}

// ---------------------------------------------------------------------------
// Kernel 1 (everything else, fused): per block of 48 query-rows:
//   phase A: fvec -> As kt8-15; 6 ball-queries/wave -> sdata; posenc -> As
//            kt0-7 (direct ds_write, replacing the old Xf HBM round-trip)
//   phase B: 3-layer MFMA MLP (B weights global->reg depth-3 prefetch),
//            final 256->3 + sigmoid.  512 blocks x 512 threads.
// LDS: As [0,49152); Hf aliases [0,24576); H2 [24576,49152);
//      sdata [49152,52992) ([48][20] floats); w3s aliases sdata (final only).
// ---------------------------------------------------------------------------
#define MAXCH 5   // up to 320 candidate slots per query (lambda ~110)

__global__ __launch_bounds__(512, 6) void fused_all(
    const float* __restrict__ points, const float* __restrict__ normals,
    const float* __restrict__ fvec, const float* __restrict__ rays,
    const float* __restrict__ ro, const float* __restrict__ parts,
    const f16* __restrict__ w0f, const f16* __restrict__ w1f,
    const f16* __restrict__ w2f,
    const float* __restrict__ b0, const float* __restrict__ b1,
    const float* __restrict__ b2,
    const float* __restrict__ W3, const float* __restrict__ b3,
    float* __restrict__ out)
{
  extern __shared__ char lds[];
  f16* As = (f16*)lds;                    // 49152 B (A panel)
  f16* Hf = (f16*)lds;                    // 24576 B (aliases As kt0-7)
  f16* H2 = (f16*)(lds + 24576);          // 24576 B (aliases As kt8-15)
  float* sdata = (float*)(lds + 49152);   // [48][20] = 3840 B
  float* w3s = (float*)(lds + 49152);     // aliases sdata (used after last barrier)

  const int tid = threadIdx.x, lane = tid & 63, wn = tid >> 6;   // wn 0..7
  const int l15 = lane & 15, l4 = lane >> 4;
  const int blk = blockIdx.x;

  // ================== phase A.1: fvec -> As kt8-15 =========================
  if (tid < 384) {
    int m = tid >> 3, sub = tid & 7, g = sub & 3, kh = sub >> 2;
    int u = m * 4 + (g ^ ((m >> 1) & 3));
    #pragma unroll
    for (int t = 0; t < 4; ++t) {
      int kf = kh * 4 + t;
      const float* src = fvec + (size_t)(blk * 48 + m) * 256 + kf * 32 + g * 8;
      float4 v0 = ((const float4*)src)[0];
      float4 v1 = ((const float4*)src)[1];
      f16 hs[8] = {(f16)v0.x, (f16)v0.y, (f16)v0.z, (f16)v0.w,
                   (f16)v1.x, (f16)v1.y, (f16)v1.z, (f16)v1.w};
      *(uint4*)(As + (8 + kf) * 1536 + u * 8) = *(uint4*)hs;
    }
  }

  // ================== phase A.2: 6 ball queries per wave ===================
  const float RQ = 0.1f * 0.1f;
  #pragma unroll 1
  for (int t = 0; t < 6; ++t) {
    const int m48 = wn * 6 + t;
    const int q = blk * 48 + m48;
    const float qx = points[3 * q], qy = points[3 * q + 1], qz = points[3 * q + 2];

    int nAcc = 0;
    float sdx = 0, sdy = 0, sdz = 0;
    float s2x = 0, s2y = 0, s2z = 0;
    float sw = 0, swx = 0, swy = 0, swz = 0;

    const int cqx = min(max((int)(qx * 10.0f), 0), 9);
    const int cqy = min(max((int)(qy * 10.0f), 0), 9);
    const int cqz = min(max((int)(qz * 10.0f), 0), 9);

    // lanes 0..8 each own one (cy,cz) row of the 3x3x3 neighborhood
    int st_l = 0, cn_l = 0;
    if (lane < 9) {
      int dz = lane / 3, dy = lane - dz * 3;
      int cz = cqz - 1 + dz, cy = cqy - 1 + dy;
      if ((unsigned)cz <= 9u && (unsigned)cy <= 9u) {
        int x0 = max(cqx - 1, 0), x1 = min(cqx + 1, 9);
        int rb = (cz * 10 + cy) * 10;
        st_l = g_cellStart[rb + x0];
        cn_l = g_cellStart[rb + x1 + 1] - st_l;
      }
    }

    int pk[9], bk[9];
    int run = 0;
    #pragma unroll
    for (int k = 0; k < 9; ++k) {
      int stk = __builtin_amdgcn_readlane(st_l, k);
      int cnk = __builtin_amdgcn_readlane(cn_l, k);
      pk[k] = run;
      bk[k] = stk - run;
      run += cnk;
    }
    const int C = run;
    const bool fb = (C > MAXCH * 64);

    if (!fb) {
      float4 sv[MAXCH];
      int iv[MAXCH];
      unsigned long long hm[MAXCH];
      #pragma unroll
      for (int ch = 0; ch < MAXCH; ++ch) {
        if (ch * 64 < C) {
          int s = ch * 64 + lane;
          int g = bk[0];
          #pragma unroll
          for (int k = 1; k < 9; ++k) g = (s >= pk[k]) ? bk[k] : g;
          float4 pt = g_sorted[min(g + s, 4095)];
          if (s >= C) {
            pt.x = 1e9f; pt.y = 1e9f; pt.z = 1e9f;
            pt.w = __int_as_float(0x7fffffff);
          }
          sv[ch] = pt;
          iv[ch] = __float_as_int(pt.w);
          float ex = pt.x - qx, ey = pt.y - qy, ez = pt.z - qz;
          float d2 = __fadd_rn(__fadd_rn(__fmul_rn(ex, ex), __fmul_rn(ey, ey)),
                               __fmul_rn(ez, ez));
          hm[ch] = __ballot(d2 < RQ);
        } else {
          hm[ch] = 0ULL;
        }
      }

      int N = 0;
      #pragma unroll
      for (int ch = 0; ch < MAXCH; ++ch) N += __popcll(hm[ch]);

      int thr = 0x7fffffff;
      if (N > 16) {
        int lo = 0, hi = 4095;
        while (lo < hi) {
          int mid = (lo + hi) >> 1;
          int c = 0;
          #pragma unroll
          for (int ch = 0; ch < MAXCH; ++ch)
            if (ch * 64 < C)
              c += __popcll(hm[ch] & __ballot(iv[ch] <= mid));
          if (c >= 16) hi = mid; else lo = mid + 1;
        }
        thr = lo;
      }

      #pragma unroll
      for (int ch = 0; ch < MAXCH; ++ch) {
        if (ch * 64 < C) {
          float4 pt = sv[ch];
          float ex = pt.x - qx, ey = pt.y - qy, ez = pt.z - qz;
          float d2 = __fadd_rn(__fadd_rn(__fmul_rn(ex, ex), __fmul_rn(ey, ey)),
                               __fmul_rn(ez, ez));
          if (d2 < RQ && iv[ch] <= thr) {
            nAcc++;
            sdx += ex; sdy += ey; sdz += ez;
            s2x += ex * ex; s2y += ey * ey; s2z += ez * ez;
            float dn = sqrtf(d2);
            float tt = dn * 10.0f;
            float w = fmaxf(1.0f - tt * tt * tt, 0.0f);
            sw += w; swx += w * pt.x; swy += w * pt.y; swz += w * pt.z;
          }
        }
      }
    } else {
      // brute-force scan in index order (wave-uniform, effectively never)
      int total = 0;
      for (int jr = 0; jr < 64; ++jr) {
        int pi = jr * 64 + lane;
        float x = parts[3 * pi], y = parts[3 * pi + 1], z = parts[3 * pi + 2];
        float ex = x - qx, ey = y - qy, ez = z - qz;
        float d2 = __fadd_rn(__fadd_rn(__fmul_rn(ex, ex), __fmul_rn(ey, ey)),
                             __fmul_rn(ez, ez));
        bool hit = d2 < RQ;
        unsigned long long m = __ballot(hit);
        int pos = __builtin_amdgcn_mbcnt_hi((unsigned)(m >> 32),
                  __builtin_amdgcn_mbcnt_lo((unsigned)m, 0u));
        if (hit && (total + pos < 16)) {
          nAcc++;
          sdx += ex; sdy += ey; sdz += ez;
          s2x += ex * ex; s2y += ey * ey; s2z += ez * ez;
          float dn = sqrtf(d2);
          float tt = dn * 10.0f;
          float w = fmaxf(1.0f - tt * tt * tt, 0.0f);
          sw += w; swx += w * x; swy += w * y; swz += w * z;
        }
        total += __popcll(m);
        if (total >= 16) break;
      }
    }

    #define WRED(x) { _Pragma("unroll") for (int o = 32; o; o >>= 1) x += __shfl_xor(x, o, 64); }
    float fn = (float)nAcc;
    WRED(fn); WRED(sdx); WRED(sdy); WRED(sdz);
    WRED(s2x); WRED(s2y); WRED(s2z);
    WRED(sw); WRED(swx); WRED(swy); WRED(swz);
    #undef WRED

    float tq = sqrtf(qx * qx + qy * qy + qz * qz) * 10.0f;
    float wpad = fmaxf(1.0f - tq * tq * tq, 0.0f);
    float density = sw + (16.0f - fn) * wpad;
    float invd = 1.0f / (density + 1e-12f);
    float spx = swx * invd, spy = swy * invd, spz = swz * invd;

    float invn = 1.0f / (fn + 1e-12f);
    float mx = sdx * invn, my = sdy * invn, mz = sdz * invn;
    float vx = fmaxf((s2x - 2.0f * mx * sdx + fn * mx * mx) * invn, 0.0f);
    float vy = fmaxf((s2y - 2.0f * my * sdy + fn * my * my) * invn, 0.0f);
    float vz = fmaxf((s2z - 2.0f * mz * sdz + fn * mz * mz) * invn, 0.0f);

    float dxx = spx - ro[0], dyy = spy - ro[1], dzz = spz - ro[2];
    float il = 1.0f / sqrtf(dxx * dxx + dyy * dyy + dzz * dzz);

    if (lane == 0) {
      float* s = sdata + m48 * 20;
      s[0] = qx; s[1] = qy; s[2] = qz; s[3] = density;
      s[4] = spx; s[5] = spy; s[6] = spz;
      s[7] = vx; s[8] = vy; s[9] = vz;
      s[10] = rays[6 * blk + 3]; s[11] = rays[6 * blk + 4]; s[12] = rays[6 * blk + 5];
      s[13] = dxx * il; s[14] = dyy * il; s[15] = dzz * il;
      s[16] = normals[3 * q]; s[17] = normals[3 * q + 1]; s[18] = normals[3 * q + 2];
    }
  }
  __syncthreads();                         // sdata visible

  // ================== phase A.3: posenc -> As kt0-7 ========================
  #pragma unroll 1
  for (int t = 0; t < 6; ++t) {
    const int m48 = wn * 6 + t;
    const float* s = sdata + m48 * 20;
    #pragma unroll
    for (int it = 0; it < 4; ++it) {
      int c = it * 64 + lane;
      int e = ftab.v[c];
      float sv_ = s[e & 31];
      float arg = sv_ * (float)(1 << ((e >> 5) & 15));
      float sn, cs;
      __sincosf(arg, &sn, &cs);
      int kind = e >> 9;
      float val = (kind == 0) ? sv_ : (kind == 1 ? sn : (kind == 2 ? cs : 0.0f));
      int kt = c >> 5, g = (c >> 3) & 3, j = c & 7;
      int u = m48 * 4 + (g ^ ((m48 >> 1) & 3));
      As[kt * 1536 + u * 8 + j] = (f16)val;
    }
  }

  // ================== phase B: MLP =========================================
  f32x4 acc[3][2];
  f16x8 bq[4][2];                          // depth-3 B pipeline (4 slots)
  f16x8 af[2][3];                          // depth-1 A pipeline

  int uB[2];
  #pragma unroll
  for (int j = 0; j < 2; ++j) {
    int n = wn * 32 + j * 16 + l15;
    uB[j] = n * 4 + (l4 ^ ((n >> 1) & 3));
  }
  int uA[3];
  #pragma unroll
  for (int i = 0; i < 3; ++i) {
    int m = i * 16 + l15;
    uA[i] = m * 4 + (l4 ^ ((m >> 1) & 3));
  }

  auto zacc = [&]() {
    #pragma unroll
    for (int i = 0; i < 3; ++i)
      #pragma unroll
      for (int j = 0; j < 2; ++j) acc[i][j] = (f32x4){0, 0, 0, 0};
  };
  auto loadB = [&](const f16* wf, int kt, f16x8* bf) {
    #pragma unroll
    for (int j = 0; j < 2; ++j)
      bf[j] = *(const f16x8*)(wf + kt * 8192 + uB[j] * 8);
  };
  auto loadA0 = [&](int kt, f16x8* a3) {
    #pragma unroll
    for (int i = 0; i < 3; ++i)
      a3[i] = *(const f16x8*)(As + kt * 1536 + uA[i] * 8);
  };
  auto loadAH = [&](const f16* Hsrc, int kt, f16x8* a3) {
    #pragma unroll
    for (int i = 0; i < 3; ++i) {
      int m = i * 16 + l15;
      int g = kt * 4 + l4;
      int u = m * 32 + (g ^ ((m >> 1) & 7));
      a3[i] = *(const f16x8*)(Hsrc + u * 8);
    }
  };
  auto mfmas = [&](f16x8* a3, f16x8* b2) {
    #pragma unroll
    for (int i = 0; i < 3; ++i)
      #pragma unroll
      for (int j = 0; j < 2; ++j)
        acc[i][j] = __builtin_amdgcn_mfma_f32_16x16x32_f16(a3[i], b2[j], acc[i][j], 0, 0, 0);
  };
  auto epilogue = [&](const float* bias_, f16* Hdst) {
    float bv[2];
    #pragma unroll
    for (int j = 0; j < 2; ++j) bv[j] = bias_[wn * 32 + j * 16 + l15];
    #pragma unroll
    for (int i = 0; i < 3; ++i) {
      #pragma unroll
      for (int r = 0; r < 4; ++r) {
        int m = i * 16 + l4 * 4 + r;
        #pragma unroll
        for (int j = 0; j < 2; ++j) {
          int n = wn * 32 + j * 16 + l15;
          float v = fmaxf(acc[i][j][r] + bv[j], 0.0f);
          int u = m * 32 + ((n >> 3) ^ ((m >> 1) & 7));
          Hdst[u * 8 + (n & 7)] = (f16)v;
        }
      }
    }
  };

  // pre-issue first three B k-tiles (in flight across the barrier)
  loadB(w0f, 0, bq[0]);
  loadB(w0f, 1, bq[1]);
  loadB(w0f, 2, bq[2]);
  __syncthreads();                         // A panel complete

  // ======================= L0: K=512, 16 kt ================================
  zacc();
  loadA0(0, af[0]);
  #pragma unroll
  for (int kt = 0; kt < 16; ++kt) {
    if (kt < 13) loadB(w0f, kt + 3, bq[(kt + 3) & 3]);
    if (kt < 15) loadA0(kt + 1, af[(kt + 1) & 1]);
    mfmas(af[kt & 1], bq[kt & 3]);
  }
  loadB(w1f, 0, bq[0]);                    // next-layer B pre-issue
  loadB(w1f, 1, bq[1]);
  loadB(w1f, 2, bq[2]);
  __syncthreads();                         // all waves done reading As
  epilogue(b0, Hf);
  __syncthreads();                         // Hf complete

  // ======================= L1: K=256, A=Hf -> H2 ===========================
  zacc();
  loadAH(Hf, 0, af[0]);
  #pragma unroll
  for (int kt = 0; kt < 8; ++kt) {
    if (kt < 5) loadB(w1f, kt + 3, bq[(kt + 3) & 3]);
    if (kt < 7) loadAH(Hf, kt + 1, af[(kt + 1) & 1]);
    mfmas(af[kt & 1], bq[kt & 3]);
  }
  loadB(w2f, 0, bq[0]);                    // next-layer B pre-issue
  loadB(w2f, 1, bq[1]);
  loadB(w2f, 2, bq[2]);
  epilogue(b1, H2);                        // H2 region dead since L0 barrier
  __syncthreads();                         // H2 complete

  // ======================= L2: K=256, A=H2 -> Hf ===========================
  zacc();
  loadAH(H2, 0, af[0]);
  #pragma unroll
  for (int kt = 0; kt < 8; ++kt) {
    if (kt < 5) loadB(w2f, kt + 3, bq[(kt + 3) & 3]);
    if (kt < 7) loadAH(H2, kt + 1, af[(kt + 1) & 1]);
    mfmas(af[kt & 1], bq[kt & 3]);
  }
  epilogue(b2, Hf);                        // no reader of Hf during L2
  __syncthreads();                         // Hf complete; sdata region free

  // ======================= final: 256 -> 3 + sigmoid =======================
  for (int i = tid; i < 768; i += 512) w3s[i] = W3[i];
  __syncthreads();

  const float B30 = b3[0], B31 = b3[1], B32 = b3[2];
  #pragma unroll 1
  for (int rr = 0; rr < 6; ++rr) {
    int m = wn * 6 + rr;
    int g = lane >> 1, j0 = (lane & 1) * 4;
    int u = m * 32 + (g ^ ((m >> 1) & 7));
    uint2 pk = *(const uint2*)(Hf + u * 8 + j0);
    f16 h4[4];
    *(uint2*)h4 = pk;
    float h0 = (float)h4[0], h1 = (float)h4[1], h2 = (float)h4[2], h3 = (float)h4[3];
    int kc = lane * 4;
    float4 wa = *(const float4*)(w3s + kc);
    float4 wb = *(const float4*)(w3s + 256 + kc);
    float4 wc = *(const float4*)(w3s + 512 + kc);
    float p0 = fmaf(h3, wa.w, fmaf(h2, wa.z, fmaf(h1, wa.y, h0 * wa.x)));
    float p1 = fmaf(h3, wb.w, fmaf(h2, wb.z, fmaf(h1, wb.y, h0 * wb.x)));
    float p2 = fmaf(h3, wc.w, fmaf(h2, wc.z, fmaf(h1, wc.y, h0 * wc.x)));
    #pragma unroll
    for (int o = 32; o; o >>= 1) {
      p0 += __shfl_xor(p0, o, 64);
      p1 += __shfl_xor(p1, o, 64);
      p2 += __shfl_xor(p2, o, 64);
    }
    if (lane == 0) {
      size_t ro_ = (size_t)(blk * 48 + m) * 3;
      out[ro_ + 0] = 1.0f / (1.0f + expf(-(p0 + B30)));
      out[ro_ + 1] = 1.0f / (1.0f + expf(-(p1 + B31)));
      out[ro_ + 2] = 1.0f / (1.0f + expf(-(p2 + B32)));
    }
  }
}

// ---------------------------------------------------------------------------
extern "C" void kernel_launch(void* const* d_in, const int* in_sizes, int n_in,
                              void* d_out, int out_size, void* d_ws, size_t ws_size,
                              hipStream_t stream) {
  const float* points  = (const float*)d_in[0];
  const float* normals = (const float*)d_in[1];
  const float* fvec    = (const float*)d_in[3];
  const float* parts   = (const float*)d_in[5];
  const float* rays    = (const float*)d_in[6];
  const float* ro      = (const float*)d_in[7];
  const float* W0 = (const float*)d_in[8];
  const float* b0 = (const float*)d_in[9];
  const float* W1 = (const float*)d_in[10];
  const float* b1 = (const float*)d_in[11];
  const float* W2 = (const float*)d_in[12];
  const float* b2 = (const float*)d_in[13];
  const float* W3 = (const float*)d_in[14];
  const float* b3 = (const float*)d_in[15];

  char* ws = (char*)d_ws;
  f16* w0f = (f16*)(ws);                    // 262144 B
  f16* w1f = (f16*)(ws + 262144);           // 131072 B
  f16* w2f = (f16*)(ws + 393216);           // 131072 B
  float* out = (float*)d_out;

  (void)hipFuncSetAttribute((const void*)fused_all,
                            hipFuncAttributeMaxDynamicSharedMemorySize, 52992);

  setup_kernel<<<257, 1024, 0, stream>>>(parts, W0, W1, W2, w0f, w1f, w2f);
  fused_all<<<512, 512, 52992, stream>>>(points, normals, fvec, rays, ro, parts,
                                         w0f, w1f, w2f,
                                         b0, b1, b2, W3, b3, out);
}

// Round 8
// 151.021 us; speedup vs baseline: 1.1090x; 1.1090x over previous
//
#include <hip/hip_runtime.h>

typedef _Float16 f16;
typedef f16 f16x8 __attribute__((ext_vector_type(8)));
typedef float f32x4 __attribute__((ext_vector_type(4)));
typedef unsigned short u16;

// ---------------------------------------------------------------------------
// Swizzled fp16 layouts (16B = 8-f16 units, BK=32 K-tiles), M-block = 48:
// A (LDS, 48x512): row m, col c -> kt=c>>5, g=(c>>3)&3, j=c&7;
//   u = m*4 + (g ^ ((m>>1)&3));  f16 off = kt*1536 + u*8 + j
// W [256,K]: n,c -> kt=c>>5, g=(c>>3)&3, j=c&7; u = n*4 + (g^((n>>1)&3));
//   off = kt*8192 + u*8 + j
// H (LDS, 48x256): m,k -> g=k>>3; u = m*32 + (g ^ ((m>>1)&7))
// ---------------------------------------------------------------------------

// ---------------------------------------------------------------------------
// Column decode table: col -> (src scalar idx, freq, kind)
// kind: 0 raw, 1 sin, 2 cos, 3 zero.  enc = src | f<<5 | kind<<9
// ---------------------------------------------------------------------------
struct FT {
  u16 v[256];
  static constexpr u16 enc(int s, int f, int k) {
    return (u16)(s | (f << 5) | (k << 9));
  }
  constexpr void p3(int base, int F, int src) {
    v[base + 0] = enc(src + 0, 0, 0);
    v[base + 1] = enc(src + 1, 0, 0);
    v[base + 2] = enc(src + 2, 0, 0);
    for (int f = 0; f < F; ++f)
      for (int r = 0; r < 6; ++r) {
        int comp = (r < 3) ? r : r - 3;
        v[base + 3 + f * 6 + r] = enc(src + comp, f, (r < 3) ? 1 : 2);
      }
  }
  constexpr void p1(int base, int F, int src) {
    v[base] = enc(src, 0, 0);
    for (int f = 0; f < F; ++f) {
      v[base + 1 + 2 * f] = enc(src, f, 1);
      v[base + 2 + 2 * f] = enc(src, f, 2);
    }
  }
  constexpr FT() : v{} {
    p3(0, 10, 0);     // hit_pos_emb   (q)          [0..62]
    p1(63, 4, 3);     // density_emb                [63..71]
    p3(72, 10, 4);    // smoothed_emb  (sp)         [72..134]
    p3(135, 10, 7);   // var_emb       (var)        [135..197]
    p3(198, 4, 10);   // hit_dir_emb   (ray dir)    [198..224]
    p3(225, 4, 13);   // dirs_emb      (dir)        [225..251]
    v[252] = enc(16, 0, 0);  // normals
    v[253] = enc(17, 0, 0);
    v[254] = enc(18, 0, 0);
    v[255] = enc(0, 0, 3);   // pad col
  }
};
__constant__ FT ftab = FT();

// ---------------------------------------------------------------------------
// Uniform grid for ball query: 10x10x10 cells, cell size 0.1 = RADIUS.
// ---------------------------------------------------------------------------
__device__ float4 g_sorted[4096];   // x,y,z, w = bitcast(original index)
__device__ int    g_cellStart[1001];

// ---------------------------------------------------------------------------
// Kernel 0 (merged setup): blocks 0..255 = weight prep fp32->fp16 swizzled;
// block 256 = grid build. Branch is block-uniform -> inner barriers safe.
// ---------------------------------------------------------------------------
__global__ __launch_bounds__(1024) void setup_kernel(
    const float* __restrict__ parts,
    const float* __restrict__ W0, const float* __restrict__ W1,
    const float* __restrict__ W2,
    f16* __restrict__ w0f, f16* __restrict__ w1f, f16* __restrict__ w2f)
{
  const int tid = threadIdx.x;
  if (blockIdx.x < 256) {
    // ---------------- weight prep ----------------
    int i = blockIdx.x * 1024 + tid;        // 0 .. 262143
    float v; f16* pf; int n, c;
    if (i < 131072) {
      n = i >> 9; c = i & 511;
      v = (c < 255) ? W0[n * 511 + c] : ((c == 255) ? 0.0f : W0[n * 511 + (c - 1)]);
      pf = w0f;
    } else if (i < 196608) {
      int j = i - 131072; n = j >> 8; c = j & 255; v = W1[j]; pf = w1f;
    } else {
      int j = i - 196608; n = j >> 8; c = j & 255; v = W2[j]; pf = w2f;
    }
    int kt = c >> 5, g = (c >> 3) & 3, jj = c & 7;
    int u = n * 4 + (g ^ ((n >> 1) & 3));
    pf[kt * 8192 + u * 8 + jj] = (f16)v;
  } else {
    // ---------------- grid build ----------------
    __shared__ int cnt[1000];
    __shared__ int pos[1000];
    __shared__ int wpre[125];
    for (int j = tid; j < 1000; j += 1024) cnt[j] = 0;
    __syncthreads();

    float px[4], py[4], pz[4];
    int cd[4];
    #pragma unroll
    for (int t = 0; t < 4; ++t) {
      int i = tid + t * 1024;
      float x = parts[3 * i], y = parts[3 * i + 1], z = parts[3 * i + 2];
      int cx = min(max((int)(x * 10.0f), 0), 9);
      int cy = min(max((int)(y * 10.0f), 0), 9);
      int cz = min(max((int)(z * 10.0f), 0), 9);
      cd[t] = (cz * 10 + cy) * 10 + cx;
      px[t] = x; py[t] = y; pz[t] = z;
      atomicAdd(&cnt[cd[t]], 1);
    }
    __syncthreads();

    if (tid < 125) {
      int s = 0;
      #pragma unroll
      for (int k = 0; k < 8; ++k) s += cnt[tid * 8 + k];
      wpre[tid] = s;
    }
    __syncthreads();
    if (tid == 0) {
      int s = 0;
      for (int c = 0; c < 125; ++c) { int t = wpre[c]; wpre[c] = s; s += t; }
    }
    __syncthreads();
    if (tid < 125) {
      int run = wpre[tid];
      #pragma unroll
      for (int k = 0; k < 8; ++k) {
        int c = tid * 8 + k;
        int n = cnt[c];
        pos[c] = run;
        g_cellStart[c] = run;
        run += n;
      }
    }
    if (tid == 0) g_cellStart[1000] = 4096;
    __syncthreads();

    #pragma unroll
    for (int t = 0; t < 4; ++t) {
      int p = atomicAdd(&pos[cd[t]], 1);
      g_sorted[p] = make_float4(px[t], py[t], pz[t], __int_as_float(tid + t * 1024));
    }
  }
}

// ---------------------------------------------------------------------------
// Kernel 1 (everything else, fused): per block of 48 query-rows:
//   phase A: fvec -> As kt8-15; 6 ball-queries/wave -> sdata; posenc -> As
//   phase B: 3-layer MFMA MLP (B weights global->reg DEPTH-2 prefetch),
//            final 256->3 + sigmoid.  512 blocks x 512 threads.
// __launch_bounds__(512, 4): VGPR cap 128 -> NO SPILLS (the (512,6) variant
// capped at ~85 VGPR and spilled 31 MB of scratch -> 73 us; don't do that).
// LDS: As [0,49152); Hf aliases [0,24576); H2 [24576,49152);
//      sdata [49152,52992) ([48][20] floats); w3s aliases sdata (final only).
// ---------------------------------------------------------------------------
#define MAXCH 5   // up to 320 candidate slots per query (lambda ~110)

__global__ __launch_bounds__(512, 4) void fused_all(
    const float* __restrict__ points, const float* __restrict__ normals,
    const float* __restrict__ fvec, const float* __restrict__ rays,
    const float* __restrict__ ro, const float* __restrict__ parts,
    const f16* __restrict__ w0f, const f16* __restrict__ w1f,
    const f16* __restrict__ w2f,
    const float* __restrict__ b0, const float* __restrict__ b1,
    const float* __restrict__ b2,
    const float* __restrict__ W3, const float* __restrict__ b3,
    float* __restrict__ out)
{
  extern __shared__ char lds[];
  f16* As = (f16*)lds;                    // 49152 B (A panel)
  f16* Hf = (f16*)lds;                    // 24576 B (aliases As kt0-7)
  f16* H2 = (f16*)(lds + 24576);          // 24576 B (aliases As kt8-15)
  float* sdata = (float*)(lds + 49152);   // [48][20] = 3840 B
  float* w3s = (float*)(lds + 49152);     // aliases sdata (used after last barrier)

  const int tid = threadIdx.x, lane = tid & 63, wn = tid >> 6;   // wn 0..7
  const int l15 = lane & 15, l4 = lane >> 4;
  const int blk = blockIdx.x;

  // ================== phase A.1: fvec -> As kt8-15 =========================
  if (tid < 384) {
    int m = tid >> 3, sub = tid & 7, g = sub & 3, kh = sub >> 2;
    int u = m * 4 + (g ^ ((m >> 1) & 3));
    #pragma unroll
    for (int t = 0; t < 4; ++t) {
      int kf = kh * 4 + t;
      const float* src = fvec + (size_t)(blk * 48 + m) * 256 + kf * 32 + g * 8;
      float4 v0 = ((const float4*)src)[0];
      float4 v1 = ((const float4*)src)[1];
      f16 hs[8] = {(f16)v0.x, (f16)v0.y, (f16)v0.z, (f16)v0.w,
                   (f16)v1.x, (f16)v1.y, (f16)v1.z, (f16)v1.w};
      *(uint4*)(As + (8 + kf) * 1536 + u * 8) = *(uint4*)hs;
    }
  }

  // ================== phase A.2: 6 ball queries per wave ===================
  const float RQ = 0.1f * 0.1f;
  #pragma unroll 1
  for (int t = 0; t < 6; ++t) {
    const int m48 = wn * 6 + t;
    const int q = blk * 48 + m48;
    const float qx = points[3 * q], qy = points[3 * q + 1], qz = points[3 * q + 2];

    int nAcc = 0;
    float sdx = 0, sdy = 0, sdz = 0;
    float s2x = 0, s2y = 0, s2z = 0;
    float sw = 0, swx = 0, swy = 0, swz = 0;

    const int cqx = min(max((int)(qx * 10.0f), 0), 9);
    const int cqy = min(max((int)(qy * 10.0f), 0), 9);
    const int cqz = min(max((int)(qz * 10.0f), 0), 9);

    // lanes 0..8 each own one (cy,cz) row of the 3x3x3 neighborhood
    int st_l = 0, cn_l = 0;
    if (lane < 9) {
      int dz = lane / 3, dy = lane - dz * 3;
      int cz = cqz - 1 + dz, cy = cqy - 1 + dy;
      if ((unsigned)cz <= 9u && (unsigned)cy <= 9u) {
        int x0 = max(cqx - 1, 0), x1 = min(cqx + 1, 9);
        int rb = (cz * 10 + cy) * 10;
        st_l = g_cellStart[rb + x0];
        cn_l = g_cellStart[rb + x1 + 1] - st_l;
      }
    }

    int pk[9], bk[9];
    int run = 0;
    #pragma unroll
    for (int k = 0; k < 9; ++k) {
      int stk = __builtin_amdgcn_readlane(st_l, k);
      int cnk = __builtin_amdgcn_readlane(cn_l, k);
      pk[k] = run;
      bk[k] = stk - run;
      run += cnk;
    }
    const int C = run;
    const bool fb = (C > MAXCH * 64);

    if (!fb) {
      float4 sv[MAXCH];
      int iv[MAXCH];
      unsigned long long hm[MAXCH];
      #pragma unroll
      for (int ch = 0; ch < MAXCH; ++ch) {
        if (ch * 64 < C) {
          int s = ch * 64 + lane;
          int g = bk[0];
          #pragma unroll
          for (int k = 1; k < 9; ++k) g = (s >= pk[k]) ? bk[k] : g;
          float4 pt = g_sorted[min(g + s, 4095)];
          if (s >= C) {
            pt.x = 1e9f; pt.y = 1e9f; pt.z = 1e9f;
            pt.w = __int_as_float(0x7fffffff);
          }
          sv[ch] = pt;
          iv[ch] = __float_as_int(pt.w);
          float ex = pt.x - qx, ey = pt.y - qy, ez = pt.z - qz;
          float d2 = __fadd_rn(__fadd_rn(__fmul_rn(ex, ex), __fmul_rn(ey, ey)),
                               __fmul_rn(ez, ez));
          hm[ch] = __ballot(d2 < RQ);
        } else {
          hm[ch] = 0ULL;
        }
      }

      int N = 0;
      #pragma unroll
      for (int ch = 0; ch < MAXCH; ++ch) N += __popcll(hm[ch]);

      int thr = 0x7fffffff;
      if (N > 16) {
        int lo = 0, hi = 4095;
        while (lo < hi) {
          int mid = (lo + hi) >> 1;
          int c = 0;
          #pragma unroll
          for (int ch = 0; ch < MAXCH; ++ch)
            if (ch * 64 < C)
              c += __popcll(hm[ch] & __ballot(iv[ch] <= mid));
          if (c >= 16) hi = mid; else lo = mid + 1;
        }
        thr = lo;
      }

      #pragma unroll
      for (int ch = 0; ch < MAXCH; ++ch) {
        if (ch * 64 < C) {
          float4 pt = sv[ch];
          float ex = pt.x - qx, ey = pt.y - qy, ez = pt.z - qz;
          float d2 = __fadd_rn(__fadd_rn(__fmul_rn(ex, ex), __fmul_rn(ey, ey)),
                               __fmul_rn(ez, ez));
          if (d2 < RQ && iv[ch] <= thr) {
            nAcc++;
            sdx += ex; sdy += ey; sdz += ez;
            s2x += ex * ex; s2y += ey * ey; s2z += ez * ez;
            float dn = sqrtf(d2);
            float tt = dn * 10.0f;
            float w = fmaxf(1.0f - tt * tt * tt, 0.0f);
            sw += w; swx += w * pt.x; swy += w * pt.y; swz += w * pt.z;
          }
        }
      }
    } else {
      // brute-force scan in index order (wave-uniform, effectively never)
      int total = 0;
      for (int jr = 0; jr < 64; ++jr) {
        int pi = jr * 64 + lane;
        float x = parts[3 * pi], y = parts[3 * pi + 1], z = parts[3 * pi + 2];
        float ex = x - qx, ey = y - qy, ez = z - qz;
        float d2 = __fadd_rn(__fadd_rn(__fmul_rn(ex, ex), __fmul_rn(ey, ey)),
                             __fmul_rn(ez, ez));
        bool hit = d2 < RQ;
        unsigned long long m = __ballot(hit);
        int pos = __builtin_amdgcn_mbcnt_hi((unsigned)(m >> 32),
                  __builtin_amdgcn_mbcnt_lo((unsigned)m, 0u));
        if (hit && (total + pos < 16)) {
          nAcc++;
          sdx += ex; sdy += ey; sdz += ez;
          s2x += ex * ex; s2y += ey * ey; s2z += ez * ez;
          float dn = sqrtf(d2);
          float tt = dn * 10.0f;
          float w = fmaxf(1.0f - tt * tt * tt, 0.0f);
          sw += w; swx += w * x; swy += w * y; swz += w * z;
        }
        total += __popcll(m);
        if (total >= 16) break;
      }
    }

    #define WRED(x) { _Pragma("unroll") for (int o = 32; o; o >>= 1) x += __shfl_xor(x, o, 64); }
    float fn = (float)nAcc;
    WRED(fn); WRED(sdx); WRED(sdy); WRED(sdz);
    WRED(s2x); WRED(s2y); WRED(s2z);
    WRED(sw); WRED(swx); WRED(swy); WRED(swz);
    #undef WRED

    float tq = sqrtf(qx * qx + qy * qy + qz * qz) * 10.0f;
    float wpad = fmaxf(1.0f - tq * tq * tq, 0.0f);
    float density = sw + (16.0f - fn) * wpad;
    float invd = 1.0f / (density + 1e-12f);
    float spx = swx * invd, spy = swy * invd, spz = swz * invd;

    float invn = 1.0f / (fn + 1e-12f);
    float mx = sdx * invn, my = sdy * invn, mz = sdz * invn;
    float vx = fmaxf((s2x - 2.0f * mx * sdx + fn * mx * mx) * invn, 0.0f);
    float vy = fmaxf((s2y - 2.0f * my * sdy + fn * my * my) * invn, 0.0f);
    float vz = fmaxf((s2z - 2.0f * mz * sdz + fn * mz * mz) * invn, 0.0f);

    float dxx = spx - ro[0], dyy = spy - ro[1], dzz = spz - ro[2];
    float il = 1.0f / sqrtf(dxx * dxx + dyy * dyy + dzz * dzz);

    if (lane == 0) {
      float* s = sdata + m48 * 20;
      s[0] = qx; s[1] = qy; s[2] = qz; s[3] = density;
      s[4] = spx; s[5] = spy; s[6] = spz;
      s[7] = vx; s[8] = vy; s[9] = vz;
      s[10] = rays[6 * blk + 3]; s[11] = rays[6 * blk + 4]; s[12] = rays[6 * blk + 5];
      s[13] = dxx * il; s[14] = dyy * il; s[15] = dzz * il;
      s[16] = normals[3 * q]; s[17] = normals[3 * q + 1]; s[18] = normals[3 * q + 2];
    }
  }
  __syncthreads();                         // sdata visible

  // ================== phase A.3: posenc -> As kt0-7 ========================
  #pragma unroll 1
  for (int t = 0; t < 6; ++t) {
    const int m48 = wn * 6 + t;
    const float* s = sdata + m48 * 20;
    #pragma unroll
    for (int it = 0; it < 4; ++it) {
      int c = it * 64 + lane;
      int e = ftab.v[c];
      float sv_ = s[e & 31];
      float arg = sv_ * (float)(1 << ((e >> 5) & 15));
      float sn, cs;
      __sincosf(arg, &sn, &cs);
      int kind = e >> 9;
      float val = (kind == 0) ? sv_ : (kind == 1 ? sn : (kind == 2 ? cs : 0.0f));
      int kt = c >> 5, g = (c >> 3) & 3, j = c & 7;
      int u = m48 * 4 + (g ^ ((m48 >> 1) & 3));
      As[kt * 1536 + u * 8 + j] = (f16)val;
    }
  }

  // ================== phase B: MLP =========================================
  f32x4 acc[3][2];
  f16x8 bq[3][2];                          // depth-2 B pipeline (3 slots)
  f16x8 af[2][3];                          // depth-1 A pipeline

  int uB[2];
  #pragma unroll
  for (int j = 0; j < 2; ++j) {
    int n = wn * 32 + j * 16 + l15;
    uB[j] = n * 4 + (l4 ^ ((n >> 1) & 3));
  }
  int uA[3];
  #pragma unroll
  for (int i = 0; i < 3; ++i) {
    int m = i * 16 + l15;
    uA[i] = m * 4 + (l4 ^ ((m >> 1) & 3));
  }

  auto zacc = [&]() {
    #pragma unroll
    for (int i = 0; i < 3; ++i)
      #pragma unroll
      for (int j = 0; j < 2; ++j) acc[i][j] = (f32x4){0, 0, 0, 0};
  };
  auto loadB = [&](const f16* wf, int kt, f16x8* bf) {
    #pragma unroll
    for (int j = 0; j < 2; ++j)
      bf[j] = *(const f16x8*)(wf + kt * 8192 + uB[j] * 8);
  };
  auto loadA0 = [&](int kt, f16x8* a3) {
    #pragma unroll
    for (int i = 0; i < 3; ++i)
      a3[i] = *(const f16x8*)(As + kt * 1536 + uA[i] * 8);
  };
  auto loadAH = [&](const f16* Hsrc, int kt, f16x8* a3) {
    #pragma unroll
    for (int i = 0; i < 3; ++i) {
      int m = i * 16 + l15;
      int g = kt * 4 + l4;
      int u = m * 32 + (g ^ ((m >> 1) & 7));
      a3[i] = *(const f16x8*)(Hsrc + u * 8);
    }
  };
  auto mfmas = [&](f16x8* a3, f16x8* b2) {
    #pragma unroll
    for (int i = 0; i < 3; ++i)
      #pragma unroll
      for (int j = 0; j < 2; ++j)
        acc[i][j] = __builtin_amdgcn_mfma_f32_16x16x32_f16(a3[i], b2[j], acc[i][j], 0, 0, 0);
  };
  auto epilogue = [&](const float* bias_, f16* Hdst) {
    float bv[2];
    #pragma unroll
    for (int j = 0; j < 2; ++j) bv[j] = bias_[wn * 32 + j * 16 + l15];
    #pragma unroll
    for (int i = 0; i < 3; ++i) {
      #pragma unroll
      for (int r = 0; r < 4; ++r) {
        int m = i * 16 + l4 * 4 + r;
        #pragma unroll
        for (int j = 0; j < 2; ++j) {
          int n = wn * 32 + j * 16 + l15;
          float v = fmaxf(acc[i][j][r] + bv[j], 0.0f);
          int u = m * 32 + ((n >> 3) ^ ((m >> 1) & 7));
          Hdst[u * 8 + (n & 7)] = (f16)v;
        }
      }
    }
  };

  // pre-issue first two B k-tiles (in flight across the barrier)
  loadB(w0f, 0, bq[0]);
  loadB(w0f, 1, bq[1]);
  __syncthreads();                         // A panel complete

  // ======================= L0: K=512, 16 kt ================================
  zacc();
  loadA0(0, af[0]);
  #pragma unroll
  for (int kt = 0; kt < 16; ++kt) {
    if (kt < 14) loadB(w0f, kt + 2, bq[(kt + 2) % 3]);
    if (kt < 15) loadA0(kt + 1, af[(kt + 1) & 1]);
    mfmas(af[kt & 1], bq[kt % 3]);
  }
  loadB(w1f, 0, bq[0]);                    // next-layer B pre-issue
  loadB(w1f, 1, bq[1]);
  __syncthreads();                         // all waves done reading As
  epilogue(b0, Hf);
  __syncthreads();                         // Hf complete

  // ======================= L1: K=256, A=Hf -> H2 ===========================
  zacc();
  loadAH(Hf, 0, af[0]);
  #pragma unroll
  for (int kt = 0; kt < 8; ++kt) {
    if (kt < 6) loadB(w1f, kt + 2, bq[(kt + 2) % 3]);
    if (kt < 7) loadAH(Hf, kt + 1, af[(kt + 1) & 1]);
    mfmas(af[kt & 1], bq[kt % 3]);
  }
  loadB(w2f, 0, bq[0]);                    // next-layer B pre-issue
  loadB(w2f, 1, bq[1]);
  epilogue(b1, H2);                        // H2 region dead since L0 barrier
  __syncthreads();                         // H2 complete

  // ======================= L2: K=256, A=H2 -> Hf ===========================
  zacc();
  loadAH(H2, 0, af[0]);
  #pragma unroll
  for (int kt = 0; kt < 8; ++kt) {
    if (kt < 6) loadB(w2f, kt + 2, bq[(kt + 2) % 3]);
    if (kt < 7) loadAH(H2, kt + 1, af[(kt + 1) & 1]);
    mfmas(af[kt & 1], bq[kt % 3]);
  }
  epilogue(b2, Hf);                        // no reader of Hf during L2
  __syncthreads();                         // Hf complete; sdata region free

  // ======================= final: 256 -> 3 + sigmoid =======================
  for (int i = tid; i < 768; i += 512) w3s[i] = W3[i];
  __syncthreads();

  const float B30 = b3[0], B31 = b3[1], B32 = b3[2];
  #pragma unroll 1
  for (int rr = 0; rr < 6; ++rr) {
    int m = wn * 6 + rr;
    int g = lane >> 1, j0 = (lane & 1) * 4;
    int u = m * 32 + (g ^ ((m >> 1) & 7));
    uint2 pk = *(const uint2*)(Hf + u * 8 + j0);
    f16 h4[4];
    *(uint2*)h4 = pk;
    float h0 = (float)h4[0], h1 = (float)h4[1], h2 = (float)h4[2], h3 = (float)h4[3];
    int kc = lane * 4;
    float4 wa = *(const float4*)(w3s + kc);
    float4 wb = *(const float4*)(w3s + 256 + kc);
    float4 wc = *(const float4*)(w3s + 512 + kc);
    float p0 = fmaf(h3, wa.w, fmaf(h2, wa.z, fmaf(h1, wa.y, h0 * wa.x)));
    float p1 = fmaf(h3, wb.w, fmaf(h2, wb.z, fmaf(h1, wb.y, h0 * wb.x)));
    float p2 = fmaf(h3, wc.w, fmaf(h2, wc.z, fmaf(h1, wc.y, h0 * wc.x)));
    #pragma unroll
    for (int o = 32; o; o >>= 1) {
      p0 += __shfl_xor(p0, o, 64);
      p1 += __shfl_xor(p1, o, 64);
      p2 += __shfl_xor(p2, o, 64);
    }
    if (lane == 0) {
      size_t ro_ = (size_t)(blk * 48 + m) * 3;
      out[ro_ + 0] = 1.0f / (1.0f + expf(-(p0 + B30)));
      out[ro_ + 1] = 1.0f / (1.0f + expf(-(p1 + B31)));
      out[ro_ + 2] = 1.0f / (1.0f + expf(-(p2 + B32)));
    }
  }
}

// ---------------------------------------------------------------------------
extern "C" void kernel_launch(void* const* d_in, const int* in_sizes, int n_in,
                              void* d_out, int out_size, void* d_ws, size_t ws_size,
                              hipStream_t stream) {
  const float* points  = (const float*)d_in[0];
  const float* normals = (const float*)d_in[1];
  const float* fvec    = (const float*)d_in[3];
  const float* parts   = (const float*)d_in[5];
  const float* rays    = (const float*)d_in[6];
  const float* ro      = (const float*)d_in[7];
  const float* W0 = (const float*)d_in[8];
  const float* b0 = (const float*)d_in[9];
  const float* W1 = (const float*)d_in[10];
  const float* b1 = (const float*)d_in[11];
  const float* W2 = (const float*)d_in[12];
  const float* b2 = (const float*)d_in[13];
  const float* W3 = (const float*)d_in[14];
  const float* b3 = (const float*)d_in[15];

  char* ws = (char*)d_ws;
  f16* w0f = (f16*)(ws);                    // 262144 B
  f16* w1f = (f16*)(ws + 262144);           // 131072 B
  f16* w2f = (f16*)(ws + 393216);           // 131072 B
  float* out = (float*)d_out;

  (void)hipFuncSetAttribute((const void*)fused_all,
                            hipFuncAttributeMaxDynamicSharedMemorySize, 52992);

  setup_kernel<<<257, 1024, 0, stream>>>(parts, W0, W1, W2, w0f, w1f, w2f);
  fused_all<<<512, 512, 52992, stream>>>(points, normals, fvec, rays, ro, parts,
                                         w0f, w1f, w2f,
                                         b0, b1, b2, W3, b3, out);
}